// Round 1
// baseline (211.912 us; speedup 1.0000x reference)
//
#include <hip/hip_runtime.h>

typedef unsigned short u16;
typedef float f32x4 __attribute__((ext_vector_type(4)));
typedef __bf16 bfx8 __attribute__((ext_vector_type(8)));
typedef u16 u16x8 __attribute__((ext_vector_type(8)));
typedef u16 u16x4 __attribute__((ext_vector_type(4)));

#define B_ 2
#define S_ 2048
#define E_ 1024
#define H_ 16
#define D_ 64

__device__ __forceinline__ u16 f2bf(float f) {
  unsigned u = __float_as_uint(f);
  u = u + 0x7FFFu + ((u >> 16) & 1u);  // RNE
  return (u16)(u >> 16);
}

// XOR swizzle for tiles with 128B rows: spreads the 8-row stripe across 16B slots.
__device__ __forceinline__ int swz128(int o) { return o ^ ((o >> 3) & 0x70); }

// ---------------- fp32 -> bf16 convert (vectorized) ----------------
__global__ void cvt_f32_bf16(const float* __restrict__ in, u16* __restrict__ out, int n4) {
  int stride = gridDim.x * blockDim.x;
  for (int i = blockIdx.x * blockDim.x + threadIdx.x; i < n4; i += stride) {
    const float4 v = reinterpret_cast<const float4*>(in)[i];
    u16x4 o = {f2bf(v.x), f2bf(v.y), f2bf(v.z), f2bf(v.w)};
    reinterpret_cast<u16x4*>(out)[i] = o;
  }
}

// ---------------- transpose + convert: out[C][R] (bf16) = in[R][C] (f32) ----------------
__global__ __launch_bounds__(256) void tcvt(const float* __restrict__ in, u16* __restrict__ out,
                                            int R, int C) {
  __shared__ float tile[64][65];
  const int ct = blockIdx.x * 64, rt = blockIdx.y * 64;
  const int tid = threadIdx.x;
#pragma unroll
  for (int p = 0; p < 4; ++p) {
    int f = p * 256 + tid;
    int row = f >> 4, c4 = (f & 15) << 2;
    const float4 v = *reinterpret_cast<const float4*>(in + (size_t)(rt + row) * C + ct + c4);
    tile[row][c4 + 0] = v.x; tile[row][c4 + 1] = v.y;
    tile[row][c4 + 2] = v.z; tile[row][c4 + 3] = v.w;
  }
  __syncthreads();
#pragma unroll
  for (int p = 0; p < 4; ++p) {
    int g = p * 256 + tid;
    int orow = g >> 4, k4 = (g & 15) << 2;
    u16x4 o = {f2bf(tile[k4 + 0][orow]), f2bf(tile[k4 + 1][orow]),
               f2bf(tile[k4 + 2][orow]), f2bf(tile[k4 + 3][orow])};
    *reinterpret_cast<u16x4*>(out + (size_t)(ct + orow) * R + rt + k4) = o;
  }
}

// ---------------- V transpose per (b,h): [S][D] -> [D][S] (bf16) ----------------
__global__ __launch_bounds__(256) void vtrans(const u16* __restrict__ V, u16* __restrict__ Vt) {
  __shared__ u16 tile[64][72];
  const int st = blockIdx.x * 64;
  const int bh = blockIdx.y;
  const int tid = threadIdx.x;
  const u16* src = V + ((size_t)bh * S_ + st) * D_;
#pragma unroll
  for (int p = 0; p < 2; ++p) {
    int g = p * 256 + tid;
    int row = g >> 3, c8 = (g & 7) << 3;
    u16x8 v = *reinterpret_cast<const u16x8*>(src + row * D_ + c8);
#pragma unroll
    for (int j = 0; j < 8; ++j) tile[row][c8 + j] = v[j];
  }
  __syncthreads();
  u16* dst = Vt + (size_t)bh * D_ * S_ + st;
#pragma unroll
  for (int p = 0; p < 2; ++p) {
    int g = p * 256 + tid;
    int d = g >> 3, s8 = (g & 7) << 3;
    u16x8 o;
#pragma unroll
    for (int j = 0; j < 8; ++j) o[j] = tile[s8 + j][d];
    *reinterpret_cast<u16x8*>(dst + (size_t)d * S_ + s8) = o;
  }
}

// ---------------- bf16 GEMM: C[M][N] = A[M][K] @ Bt[N][K]^T (+bias) ----------------
// EPI 0: scatter bf16 to K/Q/V [B][H][S][D] buffers.  EPI 1: fp32 out row-major.
template <int EPI>
__global__ __launch_bounds__(256) void gemm_bt(const u16* __restrict__ A,
                                               const u16* __restrict__ Bt,
                                               const float* __restrict__ bias, int M, int N, int K,
                                               float* __restrict__ outF, u16* __restrict__ outK,
                                               u16* __restrict__ outQ, u16* __restrict__ outV) {
  __shared__ __align__(16) u16 sA[128 * 64];
  __shared__ __align__(16) u16 sB[128 * 64];
  const int tid = threadIdx.x, lane = tid & 63;
  const int wave = tid >> 6, wr = wave >> 1, wc = wave & 1;
  const int bm = blockIdx.y * 128, bn = blockIdx.x * 128;
  f32x4 acc[4][4] = {};
  for (int k0 = 0; k0 < K; k0 += 64) {
#pragma unroll
    for (int p = 0; p < 4; ++p) {
      const int o = (p * 256 + tid) * 16;  // linear byte in 16KB tile
      const int row = o >> 7, cole = (o & 127) >> 1;
      const int d = swz128(o);
      *reinterpret_cast<u16x8*>(reinterpret_cast<char*>(sA) + d) =
          *reinterpret_cast<const u16x8*>(A + (size_t)(bm + row) * K + k0 + cole);
      *reinterpret_cast<u16x8*>(reinterpret_cast<char*>(sB) + d) =
          *reinterpret_cast<const u16x8*>(Bt + (size_t)(bn + row) * K + k0 + cole);
    }
    __syncthreads();
#pragma unroll
    for (int kc = 0; kc < 2; ++kc) {
      bfx8 af[4], bf[4];
#pragma unroll
      for (int mf = 0; mf < 4; ++mf) {
        int o = swz128(((wr * 64 + mf * 16 + (lane & 15)) << 7) + kc * 64 + ((lane >> 4) << 4));
        af[mf] = *reinterpret_cast<const bfx8*>(reinterpret_cast<const char*>(sA) + o);
      }
#pragma unroll
      for (int nf = 0; nf < 4; ++nf) {
        int o = swz128(((wc * 64 + nf * 16 + (lane & 15)) << 7) + kc * 64 + ((lane >> 4) << 4));
        bf[nf] = *reinterpret_cast<const bfx8*>(reinterpret_cast<const char*>(sB) + o);
      }
#pragma unroll
      for (int mf = 0; mf < 4; ++mf)
#pragma unroll
        for (int nf = 0; nf < 4; ++nf)
          acc[mf][nf] = __builtin_amdgcn_mfma_f32_16x16x32_bf16(af[mf], bf[nf], acc[mf][nf], 0, 0, 0);
    }
    __syncthreads();
  }
#pragma unroll
  for (int mf = 0; mf < 4; ++mf)
#pragma unroll
    for (int nf = 0; nf < 4; ++nf)
#pragma unroll
      for (int r = 0; r < 4; ++r) {
        const int row = bm + wr * 64 + mf * 16 + ((lane >> 4) << 2) + r;
        const int col = bn + wc * 64 + nf * 16 + (lane & 15);
        const float v = acc[mf][nf][r] + bias[col];
        if (EPI == 1) {
          outF[(size_t)row * N + col] = v;
        } else {
          const int chunk = col >> 10, w = col & 1023, h = w >> 6, dd = w & 63;
          const int b = row >> 11, s = row & 2047;
          const size_t idx = (((size_t)(b * H_ + h)) * S_ + s) * D_ + dd;
          u16* dst = (chunk == 0) ? outK : (chunk == 1) ? outQ : outV;
          dst[idx] = f2bf(v);
        }
      }
}

// ---------------- flash attention with ALiBi, causal ----------------
// grid (S/64, B*H); 4 waves; wave w owns q rows [q0+16w, +16). K/Vt staged in LDS (swizzled).
__global__ __launch_bounds__(256) void attn_alibi(const u16* __restrict__ Q,
                                                  const u16* __restrict__ Kb,
                                                  const u16* __restrict__ Vt,
                                                  const float* __restrict__ slopes,
                                                  u16* __restrict__ Y) {
  __shared__ __align__(16) u16 sK[64 * 64];
  __shared__ __align__(16) u16 sV[64 * 64];
  __shared__ __align__(16) u16 sP[4][16 * 72];
  const int qi = blockIdx.x, bh = blockIdx.y;
  const int b = bh >> 4, h = bh & 15;
  const int tid = threadIdx.x, lane = tid & 63, wave = tid >> 6;
  const int q0 = qi * 64;
  const float slope = slopes[h];
  const size_t headSD = (size_t)bh * S_ * D_;
  const size_t headDS = (size_t)bh * D_ * S_;
  bfx8 qf[2];
  {
    const u16* qp = Q + headSD + (size_t)(q0 + wave * 16 + (lane & 15)) * D_ + ((lane >> 4) << 3);
    qf[0] = *reinterpret_cast<const bfx8*>(qp);
    qf[1] = *reinterpret_cast<const bfx8*>(qp + 32);
  }
  float m_r[4], l_r[4];
  f32x4 o_acc[4] = {};
#pragma unroll
  for (int r = 0; r < 4; ++r) { m_r[r] = -__builtin_inff(); l_r[r] = 0.f; }
  for (int t = 0; t <= qi; ++t) {
#pragma unroll
    for (int p = 0; p < 2; ++p) {
      const int o = (p * 256 + tid) * 16;
      const int d = swz128(o);
      *reinterpret_cast<u16x8*>(reinterpret_cast<char*>(sK) + d) =
          *reinterpret_cast<const u16x8*>(Kb + headSD + t * (64 * 64) + (o >> 1));
      const int row = o >> 7, cole = (o & 127) >> 1;
      *reinterpret_cast<u16x8*>(reinterpret_cast<char*>(sV) + d) =
          *reinterpret_cast<const u16x8*>(Vt + headDS + (size_t)row * S_ + t * 64 + cole);
    }
    __syncthreads();
    f32x4 s_acc[4] = {};
#pragma unroll
    for (int kc = 0; kc < 2; ++kc)
#pragma unroll
      for (int nf = 0; nf < 4; ++nf) {
        const int o = swz128(((nf * 16 + (lane & 15)) << 7) + kc * 64 + ((lane >> 4) << 4));
        const bfx8 kf = *reinterpret_cast<const bfx8*>(reinterpret_cast<const char*>(sK) + o);
        s_acc[nf] = __builtin_amdgcn_mfma_f32_16x16x32_bf16(qf[kc], kf, s_acc[nf], 0, 0, 0);
      }
    const bool diag = (t == qi);
    float p_f[4][4];
    float rowmax[4] = {-1e30f, -1e30f, -1e30f, -1e30f};
#pragma unroll
    for (int nf = 0; nf < 4; ++nf)
#pragma unroll
      for (int r = 0; r < 4; ++r) {
        const int j = t * 64 + nf * 16 + (lane & 15);
        const int i = q0 + wave * 16 + ((lane >> 4) << 2) + r;
        float sv = s_acc[nf][r] * 0.125f + slope * (float)(j - i);
        if (diag && j > i) sv = -1e30f;
        p_f[nf][r] = sv;
        rowmax[r] = fmaxf(rowmax[r], sv);
      }
#pragma unroll
    for (int r = 0; r < 4; ++r) {
#pragma unroll
      for (int msk = 1; msk < 16; msk <<= 1)
        rowmax[r] = fmaxf(rowmax[r], __shfl_xor(rowmax[r], msk));
      const float mn = fmaxf(m_r[r], rowmax[r]);
      const float corr = __expf(m_r[r] - mn);
      m_r[r] = mn;
      l_r[r] *= corr;
#pragma unroll
      for (int nf = 0; nf < 4; ++nf) o_acc[nf][r] *= corr;
    }
    float rsum[4] = {0.f, 0.f, 0.f, 0.f};
#pragma unroll
    for (int nf = 0; nf < 4; ++nf)
#pragma unroll
      for (int r = 0; r < 4; ++r) {
        const float pe = __expf(p_f[nf][r] - m_r[r]);
        p_f[nf][r] = pe;
        rsum[r] += pe;
      }
#pragma unroll
    for (int r = 0; r < 4; ++r) {
#pragma unroll
      for (int msk = 1; msk < 16; msk <<= 1) rsum[r] += __shfl_xor(rsum[r], msk);
      l_r[r] += rsum[r];
    }
    u16* pw = sP[wave];
#pragma unroll
    for (int nf = 0; nf < 4; ++nf)
#pragma unroll
      for (int r = 0; r < 4; ++r)
        pw[(((lane >> 4) << 2) + r) * 72 + nf * 16 + (lane & 15)] = f2bf(p_f[nf][r]);
    __syncthreads();  // fences P writes (cross-lane) and prior K/V reads
    bfx8 pa[2];
#pragma unroll
    for (int kc = 0; kc < 2; ++kc)
      pa[kc] = *reinterpret_cast<const bfx8*>(reinterpret_cast<const char*>(pw) +
                                              (lane & 15) * 144 + kc * 64 + ((lane >> 4) << 4));
#pragma unroll
    for (int kc = 0; kc < 2; ++kc)
#pragma unroll
      for (int nf = 0; nf < 4; ++nf) {
        const int o = swz128(((nf * 16 + (lane & 15)) << 7) + kc * 64 + ((lane >> 4) << 4));
        const bfx8 vf = *reinterpret_cast<const bfx8*>(reinterpret_cast<const char*>(sV) + o);
        o_acc[nf] = __builtin_amdgcn_mfma_f32_16x16x32_bf16(pa[kc], vf, o_acc[nf], 0, 0, 0);
      }
    __syncthreads();  // protect sK/sV before next-iteration staging
  }
#pragma unroll
  for (int nf = 0; nf < 4; ++nf)
#pragma unroll
    for (int r = 0; r < 4; ++r) {
      const int row = q0 + wave * 16 + ((lane >> 4) << 2) + r;
      const int col = h * 64 + nf * 16 + (lane & 15);
      Y[((size_t)b * S_ + row) * E_ + col] = f2bf(o_acc[nf][r] / l_r[r]);
    }
}

extern "C" void kernel_launch(void* const* d_in, const int* in_sizes, int n_in, void* d_out,
                              int out_size, void* d_ws, size_t ws_size, hipStream_t stream) {
  (void)in_sizes; (void)n_in; (void)out_size; (void)ws_size;
  const float* x = (const float*)d_in[0];
  const float* Wkqv = (const float*)d_in[1];
  const float* bkqv = (const float*)d_in[2];
  const float* Wproj = (const float*)d_in[3];
  const float* bproj = (const float*)d_in[4];
  const float* slopes = (const float*)d_in[5];
  float* out = (float*)d_out;

  // Workspace layout (bf16 elements), total 56 MB.
  const size_t MBE = (size_t)4096 * 1024;
  u16* xb = (u16*)d_ws;                       // x in bf16           [4096][1024]
  u16* wkqvt = xb + MBE;                      // W_kqv^T bf16        [3072][1024]
  u16* wprojt = wkqvt + (size_t)3072 * 1024;  // W_proj^T bf16       [1024][1024]
  u16* kbuf = wprojt + (size_t)1024 * 1024;   // K  [B][H][S][D]
  u16* qbuf = kbuf + MBE;                     // Q  [B][H][S][D]
  u16* vbuf = qbuf + MBE;                     // V  [B][H][S][D]
  u16* vtbuf = vbuf + MBE;                    // V^T [B][H][D][S]
  u16* ybuf = vtbuf + MBE;                    // attn out [B][S][E]

  cvt_f32_bf16<<<dim3(2048), dim3(256), 0, stream>>>(x, xb, (int)(MBE / 4));
  tcvt<<<dim3(48, 16), dim3(256), 0, stream>>>(Wkqv, wkqvt, 1024, 3072);
  tcvt<<<dim3(16, 16), dim3(256), 0, stream>>>(Wproj, wprojt, 1024, 1024);
  gemm_bt<0><<<dim3(24, 32), dim3(256), 0, stream>>>(xb, wkqvt, bkqv, 4096, 3072, 1024,
                                                     (float*)nullptr, kbuf, qbuf, vbuf);
  vtrans<<<dim3(32, 32), dim3(256), 0, stream>>>(vbuf, vtbuf);
  attn_alibi<<<dim3(32, 32), dim3(256), 0, stream>>>(qbuf, kbuf, vtbuf, slopes, ybuf);
  gemm_bt<1><<<dim3(8, 32), dim3(256), 0, stream>>>(ybuf, wprojt, bproj, 4096, 1024, 1024, out,
                                                    nullptr, nullptr, nullptr);
}

// Round 2
// 172.962 us; speedup vs baseline: 1.2252x; 1.2252x over previous
//
#include <hip/hip_runtime.h>

typedef unsigned short u16;
typedef float f32x4 __attribute__((ext_vector_type(4)));
typedef __bf16 bfx8 __attribute__((ext_vector_type(8)));
typedef __bf16 bfx4 __attribute__((ext_vector_type(4)));
typedef u16 u16x8 __attribute__((ext_vector_type(8)));
typedef u16 u16x4 __attribute__((ext_vector_type(4)));

#define B_ 2
#define S_ 2048
#define E_ 1024
#define H_ 16
#define D_ 64

__device__ __forceinline__ u16 f2bf(float f) {
  unsigned u = __float_as_uint(f);
  u = u + 0x7FFFu + ((u >> 16) & 1u);  // RNE
  return (u16)(u >> 16);
}

// XOR swizzle for tiles with 128B rows: spreads the 8-row stripe across 16B slots.
__device__ __forceinline__ int swz128(int o) { return o ^ ((o >> 3) & 0x70); }

// ---------------- fp32 -> bf16 convert (vectorized) ----------------
__global__ void cvt_f32_bf16(const float* __restrict__ in, u16* __restrict__ out, int n4) {
  int stride = gridDim.x * blockDim.x;
  for (int i = blockIdx.x * blockDim.x + threadIdx.x; i < n4; i += stride) {
    const float4 v = reinterpret_cast<const float4*>(in)[i];
    u16x4 o = {f2bf(v.x), f2bf(v.y), f2bf(v.z), f2bf(v.w)};
    reinterpret_cast<u16x4*>(out)[i] = o;
  }
}

// ---------------- transpose + convert: out[C][R] (bf16) = in[R][C] (f32) ----------------
__global__ __launch_bounds__(256) void tcvt(const float* __restrict__ in, u16* __restrict__ out,
                                            int R, int C) {
  __shared__ float tile[64][65];
  const int ct = blockIdx.x * 64, rt = blockIdx.y * 64;
  const int tid = threadIdx.x;
#pragma unroll
  for (int p = 0; p < 4; ++p) {
    int f = p * 256 + tid;
    int row = f >> 4, c4 = (f & 15) << 2;
    const float4 v = *reinterpret_cast<const float4*>(in + (size_t)(rt + row) * C + ct + c4);
    tile[row][c4 + 0] = v.x; tile[row][c4 + 1] = v.y;
    tile[row][c4 + 2] = v.z; tile[row][c4 + 3] = v.w;
  }
  __syncthreads();
#pragma unroll
  for (int p = 0; p < 4; ++p) {
    int g = p * 256 + tid;
    int orow = g >> 4, k4 = (g & 15) << 2;
    u16x4 o = {f2bf(tile[k4 + 0][orow]), f2bf(tile[k4 + 1][orow]),
               f2bf(tile[k4 + 2][orow]), f2bf(tile[k4 + 3][orow])};
    *reinterpret_cast<u16x4*>(out + (size_t)(ct + orow) * R + rt + k4) = o;
  }
}

// ---------------- V transpose per (b,h): [S][D] -> [D][S] (bf16) ----------------
__global__ __launch_bounds__(256) void vtrans(const u16* __restrict__ V, u16* __restrict__ Vt) {
  __shared__ u16 tile[64][72];
  const int st = blockIdx.x * 64;
  const int bh = blockIdx.y;
  const int tid = threadIdx.x;
  const u16* src = V + ((size_t)bh * S_ + st) * D_;
#pragma unroll
  for (int p = 0; p < 2; ++p) {
    int g = p * 256 + tid;
    int row = g >> 3, c8 = (g & 7) << 3;
    u16x8 v = *reinterpret_cast<const u16x8*>(src + row * D_ + c8);
#pragma unroll
    for (int j = 0; j < 8; ++j) tile[row][c8 + j] = v[j];
  }
  __syncthreads();
  u16* dst = Vt + (size_t)bh * D_ * S_ + st;
#pragma unroll
  for (int p = 0; p < 2; ++p) {
    int g = p * 256 + tid;
    int d = g >> 3, s8 = (g & 7) << 3;
    u16x8 o;
#pragma unroll
    for (int j = 0; j < 8; ++j) o[j] = tile[s8 + j][d];
    *reinterpret_cast<u16x8*>(dst + (size_t)d * S_ + s8) = o;
  }
}

// ---------------- bf16 GEMM: C[M][N] = A[M][K] @ Bt[N][K]^T (+bias) ----------------
template <int EPI>
__global__ __launch_bounds__(256) void gemm_bt(const u16* __restrict__ A,
                                               const u16* __restrict__ Bt,
                                               const float* __restrict__ bias, int M, int N, int K,
                                               float* __restrict__ outF, u16* __restrict__ outK,
                                               u16* __restrict__ outQ, u16* __restrict__ outV) {
  __shared__ __align__(16) u16 sA[128 * 64];
  __shared__ __align__(16) u16 sB[128 * 64];
  const int tid = threadIdx.x, lane = tid & 63;
  const int wave = tid >> 6, wr = wave >> 1, wc = wave & 1;
  const int bm = blockIdx.y * 128, bn = blockIdx.x * 128;
  f32x4 acc[4][4] = {};
  for (int k0 = 0; k0 < K; k0 += 64) {
#pragma unroll
    for (int p = 0; p < 4; ++p) {
      const int o = (p * 256 + tid) * 16;  // linear byte in 16KB tile
      const int row = o >> 7, cole = (o & 127) >> 1;
      const int d = swz128(o);
      *reinterpret_cast<u16x8*>(reinterpret_cast<char*>(sA) + d) =
          *reinterpret_cast<const u16x8*>(A + (size_t)(bm + row) * K + k0 + cole);
      *reinterpret_cast<u16x8*>(reinterpret_cast<char*>(sB) + d) =
          *reinterpret_cast<const u16x8*>(Bt + (size_t)(bn + row) * K + k0 + cole);
    }
    __syncthreads();
#pragma unroll
    for (int kc = 0; kc < 2; ++kc) {
      bfx8 af[4], bf[4];
#pragma unroll
      for (int mf = 0; mf < 4; ++mf) {
        int o = swz128(((wr * 64 + mf * 16 + (lane & 15)) << 7) + kc * 64 + ((lane >> 4) << 4));
        af[mf] = *reinterpret_cast<const bfx8*>(reinterpret_cast<const char*>(sA) + o);
      }
#pragma unroll
      for (int nf = 0; nf < 4; ++nf) {
        int o = swz128(((wc * 64 + nf * 16 + (lane & 15)) << 7) + kc * 64 + ((lane >> 4) << 4));
        bf[nf] = *reinterpret_cast<const bfx8*>(reinterpret_cast<const char*>(sB) + o);
      }
#pragma unroll
      for (int mf = 0; mf < 4; ++mf)
#pragma unroll
        for (int nf = 0; nf < 4; ++nf)
          acc[mf][nf] = __builtin_amdgcn_mfma_f32_16x16x32_bf16(af[mf], bf[nf], acc[mf][nf], 0, 0, 0);
    }
    __syncthreads();
  }
#pragma unroll
  for (int mf = 0; mf < 4; ++mf)
#pragma unroll
    for (int nf = 0; nf < 4; ++nf)
#pragma unroll
      for (int r = 0; r < 4; ++r) {
        const int row = bm + wr * 64 + mf * 16 + ((lane >> 4) << 2) + r;
        const int col = bn + wc * 64 + nf * 16 + (lane & 15);
        const float v = acc[mf][nf][r] + bias[col];
        if (EPI == 1) {
          outF[(size_t)row * N + col] = v;
        } else {
          const int chunk = col >> 10, w = col & 1023, h = w >> 6, dd = w & 63;
          const int b = row >> 11, s = row & 2047;
          const size_t idx = (((size_t)(b * H_ + h)) * S_ + s) * D_ + dd;
          u16* dst = (chunk == 0) ? outK : (chunk == 1) ? outQ : outV;
          dst[idx] = f2bf(v);
        }
      }
}

// ---------------- flash attention with ALiBi, causal (swapped-operand, dbuf) ----------------
// grid (32 qtiles reversed, B*H); 4 waves; wave w owns q rows [q0+16w,+16).
// T = mfma(K,Q): lane holds P for q-row (lane&15) at keys nf*16+4g+r -> lane-local softmax.
// O^T = mfma(V^T, P^T): per-lane q matches m/l layout; P bounced via wave-private sP.
__global__ __launch_bounds__(256) void attn_alibi(const u16* __restrict__ Q,
                                                  const u16* __restrict__ Kb,
                                                  const u16* __restrict__ Vt,
                                                  const float* __restrict__ slopes,
                                                  u16* __restrict__ Y) {
  __shared__ __align__(16) u16 sK[2][4096];
  __shared__ __align__(16) u16 sV[2][4096];
  __shared__ __align__(16) __bf16 sP[4][16 * 72];
  const int qi = (int)gridDim.x - 1 - (int)blockIdx.x;  // big tiles dispatch first
  const int bh = blockIdx.y;
  const int b = bh >> 4, h = bh & 15;
  const int tid = threadIdx.x, lane = tid & 63, wave = tid >> 6;
  const int q = lane & 15, g = lane >> 4;
  const int q0 = qi * 64;
  const float slope = slopes[h];
  const size_t headSD = (size_t)bh * (S_ * D_);
  const size_t headDS = (size_t)bh * (D_ * S_);

  bfx8 qf[2];
  {
    const u16* qp = Q + headSD + (size_t)(q0 + wave * 16 + q) * D_ + (g << 3);
    qf[0] = *reinterpret_cast<const bfx8*>(qp);
    qf[1] = *reinterpret_cast<const bfx8*>(qp + 32);
  }
  const int i_local = wave * 16 + q;
  f32x4 base[4];
#pragma unroll
  for (int nf = 0; nf < 4; ++nf)
#pragma unroll
    for (int r = 0; r < 4; ++r)
      base[nf][r] = slope * (float)(nf * 16 + 4 * g + r - i_local);

  float m = -3.0e38f, l = 0.f;
  f32x4 oT[4] = {};

  // prologue: stage tile 0 into buffer 0
#pragma unroll
  for (int p = 0; p < 2; ++p) {
    const int o = (p * 256 + tid) * 16;
    const int d = swz128(o);
    *reinterpret_cast<u16x8*>(reinterpret_cast<char*>(sK[0]) + d) =
        *reinterpret_cast<const u16x8*>(Kb + headSD + (o >> 1));
    const int row = o >> 7, cole = (o & 127) >> 1;
    *reinterpret_cast<u16x8*>(reinterpret_cast<char*>(sV[0]) + d) =
        *reinterpret_cast<const u16x8*>(Vt + headDS + (size_t)row * S_ + cole);
  }
  __syncthreads();

  int cur = 0;
  for (int t = 0; t <= qi; ++t) {
    u16x8 kr[2], vr[2];
    const bool pref = (t < qi);
    if (pref) {  // issue next tile's loads early; latency hides under QK+softmax+PV
#pragma unroll
      for (int p = 0; p < 2; ++p) {
        const int o = (p * 256 + tid) * 16;
        kr[p] = *reinterpret_cast<const u16x8*>(Kb + headSD + (size_t)(t + 1) * 4096 + (o >> 1));
        const int row = o >> 7, cole = (o & 127) >> 1;
        vr[p] =
            *reinterpret_cast<const u16x8*>(Vt + headDS + (size_t)row * S_ + (t + 1) * 64 + cole);
      }
    }
    const char* sKc = reinterpret_cast<const char*>(sK[cur]);
    const char* sVc = reinterpret_cast<const char*>(sV[cur]);
    f32x4 tt[4] = {};
#pragma unroll
    for (int kc = 0; kc < 2; ++kc)
#pragma unroll
      for (int nf = 0; nf < 4; ++nf) {
        const int o = swz128(((nf * 16 + q) << 7) + kc * 64 + (g << 4));
        const bfx8 kf = *reinterpret_cast<const bfx8*>(sKc + o);
        tt[nf] = __builtin_amdgcn_mfma_f32_16x16x32_bf16(kf, qf[kc], tt[nf], 0, 0, 0);
      }
    const float tb = slope * (float)(t * 64 - q0);
    float rmax = -3.0e38f;
#pragma unroll
    for (int nf = 0; nf < 4; ++nf)
#pragma unroll
      for (int r = 0; r < 4; ++r) {
        float sv = fmaf(tt[nf][r], 0.125f, base[nf][r] + tb);
        tt[nf][r] = sv;
        rmax = fmaxf(rmax, sv);
      }
    if (t == qi) {  // causal mask on the diagonal tile only
      rmax = -3.0e38f;
#pragma unroll
      for (int nf = 0; nf < 4; ++nf)
#pragma unroll
        for (int r = 0; r < 4; ++r) {
          if (nf * 16 + 4 * g + r > i_local) tt[nf][r] = -1e30f;
          rmax = fmaxf(rmax, tt[nf][r]);
        }
    }
    rmax = fmaxf(rmax, __shfl_xor(rmax, 16));
    rmax = fmaxf(rmax, __shfl_xor(rmax, 32));
    const float mnew = fmaxf(m, rmax);
    const float corr = __expf(m - mnew);
    m = mnew;
    float rsum = 0.f;
#pragma unroll
    for (int nf = 0; nf < 4; ++nf)
#pragma unroll
      for (int r = 0; r < 4; ++r) {
        const float e = __expf(tt[nf][r] - m);
        tt[nf][r] = e;
        rsum += e;
      }
    rsum += __shfl_xor(rsum, 16);
    rsum += __shfl_xor(rsum, 32);
    l = l * corr + rsum;
#pragma unroll
    for (int nf = 0; nf < 4; ++nf) oT[nf] *= corr;

    // P -> wave-private sP (no barrier needed; within-wave lgkmcnt ordering)
    __bf16* pw = &sP[wave][q * 72];
#pragma unroll
    for (int nf = 0; nf < 4; ++nf) {
      bfx4 w = {(__bf16)tt[nf][0], (__bf16)tt[nf][1], (__bf16)tt[nf][2], (__bf16)tt[nf][3]};
      *reinterpret_cast<bfx4*>(pw + nf * 16 + 4 * g) = w;
    }
    bfx8 pa[2];
#pragma unroll
    for (int kc = 0; kc < 2; ++kc)
      pa[kc] = *reinterpret_cast<const bfx8*>(reinterpret_cast<const char*>(sP[wave]) + q * 144 +
                                              kc * 64 + (g << 4));
#pragma unroll
    for (int kc = 0; kc < 2; ++kc)
#pragma unroll
      for (int nf = 0; nf < 4; ++nf) {
        const int o = swz128(((nf * 16 + q) << 7) + kc * 64 + (g << 4));
        const bfx8 vf = *reinterpret_cast<const bfx8*>(sVc + o);
        oT[nf] = __builtin_amdgcn_mfma_f32_16x16x32_bf16(vf, pa[kc], oT[nf], 0, 0, 0);
      }
    if (pref) {  // write prefetched tile into the other buffer
#pragma unroll
      for (int p = 0; p < 2; ++p) {
        const int o = (p * 256 + tid) * 16;
        const int d = swz128(o);
        *reinterpret_cast<u16x8*>(reinterpret_cast<char*>(sK[cur ^ 1]) + d) = kr[p];
        *reinterpret_cast<u16x8*>(reinterpret_cast<char*>(sV[cur ^ 1]) + d) = vr[p];
      }
    }
    __syncthreads();  // single barrier per iteration
    cur ^= 1;
  }
  const float rl = 1.0f / l;
  const int row = q0 + wave * 16 + q;
#pragma unroll
  for (int nf = 0; nf < 4; ++nf) {
    bfx4 w = {(__bf16)(oT[nf][0] * rl), (__bf16)(oT[nf][1] * rl), (__bf16)(oT[nf][2] * rl),
              (__bf16)(oT[nf][3] * rl)};
    const int col = h * 64 + nf * 16 + g * 4;
    *reinterpret_cast<bfx4*>(reinterpret_cast<char*>(Y) + (((size_t)b * S_ + row) * E_ + col) * 2) =
        w;
  }
}

extern "C" void kernel_launch(void* const* d_in, const int* in_sizes, int n_in, void* d_out,
                              int out_size, void* d_ws, size_t ws_size, hipStream_t stream) {
  (void)in_sizes; (void)n_in; (void)out_size; (void)ws_size;
  const float* x = (const float*)d_in[0];
  const float* Wkqv = (const float*)d_in[1];
  const float* bkqv = (const float*)d_in[2];
  const float* Wproj = (const float*)d_in[3];
  const float* bproj = (const float*)d_in[4];
  const float* slopes = (const float*)d_in[5];
  float* out = (float*)d_out;

  const size_t MBE = (size_t)4096 * 1024;
  u16* xb = (u16*)d_ws;                       // x in bf16           [4096][1024]
  u16* wkqvt = xb + MBE;                      // W_kqv^T bf16        [3072][1024]
  u16* wprojt = wkqvt + (size_t)3072 * 1024;  // W_proj^T bf16       [1024][1024]
  u16* kbuf = wprojt + (size_t)1024 * 1024;   // K  [B][H][S][D]
  u16* qbuf = kbuf + MBE;                     // Q  [B][H][S][D]
  u16* vbuf = qbuf + MBE;                     // V  [B][H][S][D]
  u16* vtbuf = vbuf + MBE;                    // V^T [B][H][D][S]
  u16* ybuf = vtbuf + MBE;                    // attn out [B][S][E]

  cvt_f32_bf16<<<dim3(2048), dim3(256), 0, stream>>>(x, xb, (int)(MBE / 4));
  tcvt<<<dim3(48, 16), dim3(256), 0, stream>>>(Wkqv, wkqvt, 1024, 3072);
  tcvt<<<dim3(16, 16), dim3(256), 0, stream>>>(Wproj, wprojt, 1024, 1024);
  gemm_bt<0><<<dim3(24, 32), dim3(256), 0, stream>>>(xb, wkqvt, bkqv, 4096, 3072, 1024,
                                                     (float*)nullptr, kbuf, qbuf, vbuf);
  vtrans<<<dim3(32, 32), dim3(256), 0, stream>>>(vbuf, vtbuf);
  attn_alibi<<<dim3(32, 32), dim3(256), 0, stream>>>(qbuf, kbuf, vtbuf, slopes, ybuf);
  gemm_bt<1><<<dim3(8, 32), dim3(256), 0, stream>>>(ybuf, wprojt, bproj, 4096, 1024, 1024, out,
                                                    nullptr, nullptr, nullptr);
}

// Round 3
// 145.405 us; speedup vs baseline: 1.4574x; 1.1895x over previous
//
#include <hip/hip_runtime.h>

typedef unsigned short u16;
typedef float f32x4 __attribute__((ext_vector_type(4)));
typedef __bf16 bfx8 __attribute__((ext_vector_type(8)));
typedef __bf16 bfx4 __attribute__((ext_vector_type(4)));
typedef u16 u16x8 __attribute__((ext_vector_type(8)));
typedef u16 u16x4 __attribute__((ext_vector_type(4)));

#define B_ 2
#define S_ 2048
#define E_ 1024
#define H_ 16
#define D_ 64

__device__ __forceinline__ u16 f2bf(float f) {
  unsigned u = __float_as_uint(f);
  u = u + 0x7FFFu + ((u >> 16) & 1u);  // RNE
  return (u16)(u >> 16);
}

// XOR swizzle for tiles with 128B rows: byte ^= ((row&7)<<4).
__device__ __forceinline__ int swz128(int o) { return o ^ ((o >> 3) & 0x70); }

// async global->LDS, 16B per lane; LDS dest must be wave-uniform base (HW adds lane*16).
__device__ __forceinline__ void gload16(const void* g, void* l) {
  __builtin_amdgcn_global_load_lds((const __attribute__((address_space(1))) void*)g,
                                   (__attribute__((address_space(3))) void*)l, 16, 0, 0);
}

// ---------------- fp32 -> bf16 convert (vectorized) ----------------
__global__ void cvt_f32_bf16(const float* __restrict__ in, u16* __restrict__ out, int n4) {
  int stride = gridDim.x * blockDim.x;
  for (int i = blockIdx.x * blockDim.x + threadIdx.x; i < n4; i += stride) {
    const float4 v = reinterpret_cast<const float4*>(in)[i];
    u16x4 o = {f2bf(v.x), f2bf(v.y), f2bf(v.z), f2bf(v.w)};
    reinterpret_cast<u16x4*>(out)[i] = o;
  }
}

// ---------------- transpose + convert: out[C][R] (bf16) = in[R][C] (f32) ----------------
__global__ __launch_bounds__(256) void tcvt(const float* __restrict__ in, u16* __restrict__ out,
                                            int R, int C) {
  __shared__ float tile[64][65];
  const int ct = blockIdx.x * 64, rt = blockIdx.y * 64;
  const int tid = threadIdx.x;
#pragma unroll
  for (int p = 0; p < 4; ++p) {
    int f = p * 256 + tid;
    int row = f >> 4, c4 = (f & 15) << 2;
    const float4 v = *reinterpret_cast<const float4*>(in + (size_t)(rt + row) * C + ct + c4);
    tile[row][c4 + 0] = v.x; tile[row][c4 + 1] = v.y;
    tile[row][c4 + 2] = v.z; tile[row][c4 + 3] = v.w;
  }
  __syncthreads();
#pragma unroll
  for (int p = 0; p < 4; ++p) {
    int g = p * 256 + tid;
    int orow = g >> 4, k4 = (g & 15) << 2;
    u16x4 o = {f2bf(tile[k4 + 0][orow]), f2bf(tile[k4 + 1][orow]),
               f2bf(tile[k4 + 2][orow]), f2bf(tile[k4 + 3][orow])};
    *reinterpret_cast<u16x4*>(out + (size_t)(ct + orow) * R + rt + k4) = o;
  }
}

// ---------------- V transpose per (b,h): [S][D] -> [D][S] (bf16) ----------------
__global__ __launch_bounds__(256) void vtrans(const u16* __restrict__ V, u16* __restrict__ Vt) {
  __shared__ u16 tile[64][72];
  const int st = blockIdx.x * 64;
  const int bh = blockIdx.y;
  const int tid = threadIdx.x;
  const u16* src = V + ((size_t)bh * S_ + st) * D_;
#pragma unroll
  for (int p = 0; p < 2; ++p) {
    int g = p * 256 + tid;
    int row = g >> 3, c8 = (g & 7) << 3;
    u16x8 v = *reinterpret_cast<const u16x8*>(src + row * D_ + c8);
#pragma unroll
    for (int j = 0; j < 8; ++j) tile[row][c8 + j] = v[j];
  }
  __syncthreads();
  u16* dst = Vt + (size_t)bh * D_ * S_ + st;
#pragma unroll
  for (int p = 0; p < 2; ++p) {
    int g = p * 256 + tid;
    int d = g >> 3, s8 = (g & 7) << 3;
    u16x8 o;
#pragma unroll
    for (int j = 0; j < 8; ++j) o[j] = tile[s8 + j][d];
    *reinterpret_cast<u16x8*>(dst + (size_t)d * S_ + s8) = o;
  }
}

// ---------------- bf16 GEMM: C[M][N] = A[M][K] @ Bt[N][K]^T (+bias) ----------------
// Staging via global_load_lds w=16 (m97 structure): linear LDS dest, pre-swizzled source.
// Lane l of chunk c (1KB) fetches logical row 8c+(l>>3), col16 = (l&7)^(l>>3); readers swz128.
template <int EPI>
__global__ __launch_bounds__(256) void gemm_bt(const u16* __restrict__ A,
                                               const u16* __restrict__ Bt,
                                               const float* __restrict__ bias, int M, int N, int K,
                                               float* __restrict__ outF, u16* __restrict__ outK,
                                               u16* __restrict__ outQ, u16* __restrict__ outV) {
  __shared__ __align__(16) u16 sA[128 * 64];
  __shared__ __align__(16) u16 sB[128 * 64];
  const int tid = threadIdx.x, lane = tid & 63;
  const int wave = tid >> 6, wr = wave >> 1, wc = wave & 1;
  const int bm = blockIdx.y * 128, bn = blockIdx.x * 128;
  const int r8 = lane >> 3, c16 = (lane & 7) ^ r8;
  f32x4 acc[4][4] = {};
  for (int k0 = 0; k0 < K; k0 += 64) {
#pragma unroll
    for (int i = 0; i < 4; ++i) {
      const int c = wave * 4 + i;
      const int row = c * 8 + r8;
      gload16(A + (size_t)(bm + row) * K + k0 + c16 * 8, (char*)sA + c * 1024);
      gload16(Bt + (size_t)(bn + row) * K + k0 + c16 * 8, (char*)sB + c * 1024);
    }
    __syncthreads();  // vmcnt(0) drain: tile ready
#pragma unroll
    for (int kc = 0; kc < 2; ++kc) {
      bfx8 af[4], bf[4];
#pragma unroll
      for (int mf = 0; mf < 4; ++mf) {
        int o = swz128(((wr * 64 + mf * 16 + (lane & 15)) << 7) + kc * 64 + ((lane >> 4) << 4));
        af[mf] = *reinterpret_cast<const bfx8*>(reinterpret_cast<const char*>(sA) + o);
      }
#pragma unroll
      for (int nf = 0; nf < 4; ++nf) {
        int o = swz128(((wc * 64 + nf * 16 + (lane & 15)) << 7) + kc * 64 + ((lane >> 4) << 4));
        bf[nf] = *reinterpret_cast<const bfx8*>(reinterpret_cast<const char*>(sB) + o);
      }
#pragma unroll
      for (int mf = 0; mf < 4; ++mf)
#pragma unroll
        for (int nf = 0; nf < 4; ++nf)
          acc[mf][nf] = __builtin_amdgcn_mfma_f32_16x16x32_bf16(af[mf], bf[nf], acc[mf][nf], 0, 0, 0);
    }
    __syncthreads();  // protect LDS before next stage
  }
#pragma unroll
  for (int mf = 0; mf < 4; ++mf)
#pragma unroll
    for (int nf = 0; nf < 4; ++nf)
#pragma unroll
      for (int r = 0; r < 4; ++r) {
        const int row = bm + wr * 64 + mf * 16 + ((lane >> 4) << 2) + r;
        const int col = bn + wc * 64 + nf * 16 + (lane & 15);
        const float v = acc[mf][nf][r] + bias[col];
        if (EPI == 1) {
          outF[(size_t)row * N + col] = v;
        } else {
          const int chunk = col >> 10, w = col & 1023, h = w >> 6, dd = w & 63;
          const int b = row >> 11, s = row & 2047;
          const size_t idx = (((size_t)(b * H_ + h)) * S_ + s) * D_ + dd;
          u16* dst = (chunk == 0) ? outK : (chunk == 1) ? outQ : outV;
          dst[idx] = f2bf(v);
        }
      }
}

// ---------------- flash attention with ALiBi, causal ----------------
// QBLK=128 (wave owns 32 q rows = 2 fragments), KVBLK=64, swapped-operand softmax.
// 512 blocks, id->(bh,qi) chosen so CU pairs {c,c+256} get qi and 15-qi => 36 iters/CU uniform.
// K/V staged via global_load_lds (dbuf); sP swizzled (swz128).
__global__ __launch_bounds__(256) void attn_alibi(const u16* __restrict__ Q,
                                                  const u16* __restrict__ Kb,
                                                  const u16* __restrict__ Vt,
                                                  const float* __restrict__ slopes,
                                                  u16* __restrict__ Y) {
  __shared__ __align__(16) u16 sK[2][4096];
  __shared__ __align__(16) u16 sV[2][4096];
  __shared__ __align__(16) __bf16 sP[4][32 * 64];
  const int id = blockIdx.x;
  const int hi = id >> 8, rem = id & 255;
  const int qi = hi ? (rem & 15) : (15 - (rem & 15));
  const int bh = (rem >> 4) + (hi << 4);
  const int b = bh >> 4, h = bh & 15;
  const int tid = threadIdx.x, lane = tid & 63, wave = tid >> 6;
  const int q = lane & 15, g = lane >> 4;
  const int q0 = qi * 128;
  const float slope = slopes[h];
  const size_t headSD = (size_t)bh * (S_ * D_);
  const size_t headDS = (size_t)bh * (D_ * S_);
  const int nt = 2 * qi + 2;
  const int r8 = lane >> 3, c16 = (lane & 7) ^ r8;

  bfx8 qf[2][2];
#pragma unroll
  for (int u = 0; u < 2; ++u) {
    const u16* qp = Q + headSD + (size_t)(q0 + wave * 32 + u * 16 + q) * D_ + (g << 3);
    qf[u][0] = *reinterpret_cast<const bfx8*>(qp);
    qf[u][1] = *reinterpret_cast<const bfx8*>(qp + 32);
  }
  f32x4 kb[4];
#pragma unroll
  for (int nf = 0; nf < 4; ++nf)
#pragma unroll
    for (int r = 0; r < 4; ++r) kb[nf][r] = slope * (float)(nf * 16 + 4 * g + r);
  const int irow[2] = {q0 + wave * 32 + q, q0 + wave * 32 + 16 + q};

  float m[2] = {-3.0e38f, -3.0e38f}, l[2] = {0.f, 0.f};
  f32x4 oT[2][4] = {};

  auto stage = [&](int t, int buf) {
#pragma unroll
    for (int i = 0; i < 2; ++i) {
      const int c = wave * 2 + i;          // chunk 0..7 of the 8KB tile
      const int row = c * 8 + r8;          // K: key row; V: d row
      gload16(Kb + headSD + (size_t)t * 4096 + row * 64 + c16 * 8, (char*)sK[buf] + c * 1024);
      gload16(Vt + headDS + (size_t)row * S_ + t * 64 + c16 * 8, (char*)sV[buf] + c * 1024);
    }
  };

  stage(0, 0);
  __syncthreads();
  int cur = 0;
  for (int t = 0; t < nt; ++t) {
    if (t + 1 < nt) stage(t + 1, cur ^ 1);  // in flight across compute; drained at barrier
    if (t * 64 <= q0 + wave * 32 + 31) {    // wave-level skip of fully-masked tiles
      const char* sKc = reinterpret_cast<const char*>(sK[cur]);
      const char* sVc = reinterpret_cast<const char*>(sV[cur]);
      f32x4 tt[2][4] = {};
#pragma unroll
      for (int kc = 0; kc < 2; ++kc) {
        bfx8 kf[4];
#pragma unroll
        for (int nf = 0; nf < 4; ++nf)
          kf[nf] = *reinterpret_cast<const bfx8*>(sKc +
                                                  swz128(((nf * 16 + q) << 7) + kc * 64 + (g << 4)));
#pragma unroll
        for (int u = 0; u < 2; ++u)
#pragma unroll
          for (int nf = 0; nf < 4; ++nf)
            tt[u][nf] = __builtin_amdgcn_mfma_f32_16x16x32_bf16(kf[nf], qf[u][kc], tt[u][nf], 0, 0, 0);
      }
      const float tb = slope * (float)(t * 64);
#pragma unroll
      for (int u = 0; u < 2; ++u) {
        const float off = tb - slope * (float)irow[u];
        float rmax = -3.0e38f;
#pragma unroll
        for (int nf = 0; nf < 4; ++nf)
#pragma unroll
          for (int r = 0; r < 4; ++r) {
            const float sv = fmaf(tt[u][nf][r], 0.125f, kb[nf][r] + off);
            tt[u][nf][r] = sv;
            rmax = fmaxf(rmax, sv);
          }
        const int irel = irow[u] - t * 64;
        if (irel < 63) {  // diagonal fragment: apply causal mask
          rmax = -3.0e38f;
#pragma unroll
          for (int nf = 0; nf < 4; ++nf)
#pragma unroll
            for (int r = 0; r < 4; ++r) {
              if (nf * 16 + 4 * g + r > irel) tt[u][nf][r] = -3.0e38f;
              rmax = fmaxf(rmax, tt[u][nf][r]);
            }
        }
        rmax = fmaxf(rmax, __shfl_xor(rmax, 16));
        rmax = fmaxf(rmax, __shfl_xor(rmax, 32));
        const float mnew = fmaxf(m[u], rmax);
        const float corr = __expf(m[u] - mnew);
        m[u] = mnew;
        float rsum = 0.f;
#pragma unroll
        for (int nf = 0; nf < 4; ++nf)
#pragma unroll
          for (int r = 0; r < 4; ++r) {
            const float e = __expf(tt[u][nf][r] - m[u]);
            tt[u][nf][r] = e;
            rsum += e;
          }
        rsum += __shfl_xor(rsum, 16);
        rsum += __shfl_xor(rsum, 32);
        l[u] = l[u] * corr + rsum;
#pragma unroll
        for (int nf = 0; nf < 4; ++nf) oT[u][nf] *= corr;
        char* pw = reinterpret_cast<char*>(sP[wave]);
#pragma unroll
        for (int nf = 0; nf < 4; ++nf) {
          bfx4 w = {(__bf16)tt[u][nf][0], (__bf16)tt[u][nf][1], (__bf16)tt[u][nf][2],
                    (__bf16)tt[u][nf][3]};
          *reinterpret_cast<bfx4*>(pw + swz128(((u * 16 + q) << 7) + nf * 32 + g * 8)) = w;
        }
      }
      const char* pr = reinterpret_cast<const char*>(sP[wave]);
#pragma unroll
      for (int u = 0; u < 2; ++u) {
        bfx8 pa[2];
#pragma unroll
        for (int kc = 0; kc < 2; ++kc)
          pa[kc] = *reinterpret_cast<const bfx8*>(pr +
                                                  swz128(((u * 16 + q) << 7) + kc * 64 + (g << 4)));
#pragma unroll
        for (int kc = 0; kc < 2; ++kc)
#pragma unroll
          for (int nf = 0; nf < 4; ++nf) {
            const bfx8 vf = *reinterpret_cast<const bfx8*>(
                sVc + swz128(((nf * 16 + q) << 7) + kc * 64 + (g << 4)));
            oT[u][nf] = __builtin_amdgcn_mfma_f32_16x16x32_bf16(vf, pa[kc], oT[u][nf], 0, 0, 0);
          }
      }
    }
    __syncthreads();  // drains prefetch vmcnt; protects sK/sV swap
    cur ^= 1;
  }
#pragma unroll
  for (int u = 0; u < 2; ++u) {
    const float rl = 1.0f / l[u];
    const int row = irow[u];
#pragma unroll
    for (int nf = 0; nf < 4; ++nf) {
      bfx4 w = {(__bf16)(oT[u][nf][0] * rl), (__bf16)(oT[u][nf][1] * rl),
                (__bf16)(oT[u][nf][2] * rl), (__bf16)(oT[u][nf][3] * rl)};
      const int col = h * 64 + nf * 16 + g * 4;
      *reinterpret_cast<bfx4*>(reinterpret_cast<char*>(Y) +
                               (((size_t)b * S_ + row) * E_ + col) * 2) = w;
    }
  }
}

extern "C" void kernel_launch(void* const* d_in, const int* in_sizes, int n_in, void* d_out,
                              int out_size, void* d_ws, size_t ws_size, hipStream_t stream) {
  (void)in_sizes; (void)n_in; (void)out_size; (void)ws_size;
  const float* x = (const float*)d_in[0];
  const float* Wkqv = (const float*)d_in[1];
  const float* bkqv = (const float*)d_in[2];
  const float* Wproj = (const float*)d_in[3];
  const float* bproj = (const float*)d_in[4];
  const float* slopes = (const float*)d_in[5];
  float* out = (float*)d_out;

  const size_t MBE = (size_t)4096 * 1024;
  u16* xb = (u16*)d_ws;                       // x in bf16           [4096][1024]
  u16* wkqvt = xb + MBE;                      // W_kqv^T bf16        [3072][1024]
  u16* wprojt = wkqvt + (size_t)3072 * 1024;  // W_proj^T bf16       [1024][1024]
  u16* kbuf = wprojt + (size_t)1024 * 1024;   // K  [B][H][S][D]
  u16* qbuf = kbuf + MBE;                     // Q  [B][H][S][D]
  u16* vbuf = qbuf + MBE;                     // V  [B][H][S][D]
  u16* vtbuf = vbuf + MBE;                    // V^T [B][H][D][S]
  u16* ybuf = vtbuf + MBE;                    // attn out [B][S][E]

  cvt_f32_bf16<<<dim3(2048), dim3(256), 0, stream>>>(x, xb, (int)(MBE / 4));
  tcvt<<<dim3(48, 16), dim3(256), 0, stream>>>(Wkqv, wkqvt, 1024, 3072);
  tcvt<<<dim3(16, 16), dim3(256), 0, stream>>>(Wproj, wprojt, 1024, 1024);
  gemm_bt<0><<<dim3(24, 32), dim3(256), 0, stream>>>(xb, wkqvt, bkqv, 4096, 3072, 1024,
                                                     (float*)nullptr, kbuf, qbuf, vbuf);
  vtrans<<<dim3(32, 32), dim3(256), 0, stream>>>(vbuf, vtbuf);
  attn_alibi<<<dim3(512), dim3(256), 0, stream>>>(qbuf, kbuf, vtbuf, slopes, ybuf);
  gemm_bt<1><<<dim3(8, 32), dim3(256), 0, stream>>>(ybuf, wprojt, bproj, 4096, 1024, 1024, out,
                                                    nullptr, nullptr, nullptr);
}